// Round 10
// baseline (456.578 us; speedup 1.0000x reference)
//
#include <hip/hip_runtime.h>
#include <math.h>

#define NUM_USERS 100000
#define NUM_ITEMS 50000
#define N_NODES   150000   // NUM_USERS + NUM_ITEMS
#define LATENT    64
#define N_EDGES   2400000
#define BATCH     16384

// Multisplit fill: 4096-edge chunks, 512-row buckets
#define CHUNK 4096
#define NBLK  ((N_EDGES + CHUNK - 1) / CHUNK)   // 586
#define NBKT  ((N_NODES + 511) / 512)           // 293

// bf16 helpers (values small/finite; RNE)
__device__ __forceinline__ unsigned short f2bf(float f) {
    unsigned u = __float_as_uint(f);
    u = (u + 0x7FFF + ((u >> 16) & 1)) >> 16;
    return (unsigned short)u;
}
__device__ __forceinline__ float bf2f(unsigned short h) {
    return __uint_as_float(((unsigned)h) << 16);
}

// ---------------------------------------------------------------------------
// table = bf16(concat(user_emb, item_emb))
// ---------------------------------------------------------------------------
__global__ void k_concat_bf16(const float4* __restrict__ ue,
                              const float4* __restrict__ ie,
                              ushort4* __restrict__ cur) {
    int i = blockIdx.x * blockDim.x + threadIdx.x;
    const int nU4 = NUM_USERS * (LATENT / 4);
    const int nT4 = N_NODES   * (LATENT / 4);
    if (i >= nT4) return;
    float4 v = (i < nU4) ? ue[i] : ie[i - nU4];
    ushort4 o;
    o.x = f2bf(v.x); o.y = f2bf(v.y); o.z = f2bf(v.z); o.w = f2bf(v.w);
    cur[i] = o;
}

// ---------------------------------------------------------------------------
// vsel[b, 0:64] = user_emb[users[b]] ; vsel[b,64:128] = item_emb[items[b]]
// ---------------------------------------------------------------------------
__global__ void k_sel_init(const int* __restrict__ users,
                           const int* __restrict__ items,
                           const float* __restrict__ ue,
                           const float* __restrict__ ie,
                           float* __restrict__ vsel) {
    int t = blockIdx.x * blockDim.x + threadIdx.x;
    int b = t >> 6, d = t & 63;
    vsel[b * 128 + d]      = ue[users[b] * 64 + d];
    vsel[b * 128 + 64 + d] = ie[items[b] * 64 + d];
}

// ---------------------------------------------------------------------------
// Multisplit p1a: per-block bucket histogram -> cmat[bucket][block]
// ---------------------------------------------------------------------------
__global__ __launch_bounds__(256) void k_p1a(const int* __restrict__ rows,
                                             int* __restrict__ cmat) {
    __shared__ int hist[NBKT];
    for (int i = threadIdx.x; i < NBKT; i += 256) hist[i] = 0;
    __syncthreads();
    int e0 = blockIdx.x * CHUNK;
    int cnt = min(CHUNK, N_EDGES - e0);
    for (int t = threadIdx.x; t < cnt; t += 256)
        atomicAdd(&hist[rows[e0 + t] >> 9], 1);
    __syncthreads();
    for (int i = threadIdx.x; i < NBKT; i += 256)
        cmat[i * NBLK + blockIdx.x] = hist[i];
}

// ---------------------------------------------------------------------------
// Multisplit p1b: per-bucket exclusive scan over blocks; emit bucket total.
// ---------------------------------------------------------------------------
__global__ __launch_bounds__(1024) void k_p1b(int* __restrict__ cmat,
                                              int* __restrict__ btotal) {
    __shared__ int sh[1024];
    int k = blockIdx.x;
    int v = (threadIdx.x < NBLK) ? cmat[k * NBLK + threadIdx.x] : 0;
    sh[threadIdx.x] = v;
    __syncthreads();
    for (int off = 1; off < 1024; off <<= 1) {
        int t = (threadIdx.x >= off) ? sh[threadIdx.x - off] : 0;
        __syncthreads();
        sh[threadIdx.x] += t;
        __syncthreads();
    }
    if (threadIdx.x < NBLK)
        cmat[k * NBLK + threadIdx.x] = sh[threadIdx.x] - v;   // exclusive
    if (threadIdx.x == 1023) btotal[k] = sh[1023];
}

// ---------------------------------------------------------------------------
// Bucket-base scan: exclusive scan of 293 bucket totals -> bbase[0..NBKT]
// ---------------------------------------------------------------------------
__global__ __launch_bounds__(512) void k_bscan(const int* __restrict__ btotal,
                                               int* __restrict__ bbase) {
    __shared__ int sh[512];
    int v = (threadIdx.x < NBKT) ? btotal[threadIdx.x] : 0;
    sh[threadIdx.x] = v;
    __syncthreads();
    for (int off = 1; off < 512; off <<= 1) {
        int t = (threadIdx.x >= off) ? sh[threadIdx.x - off] : 0;
        __syncthreads();
        sh[threadIdx.x] += t;
        __syncthreads();
    }
    if (threadIdx.x < NBKT) bbase[threadIdx.x] = sh[threadIdx.x] - v;
    if (threadIdx.x == NBKT) bbase[NBKT] = N_EDGES;
}

// ---------------------------------------------------------------------------
// Multisplit p1c: re-read chunk, bin records in LDS, flush bucket-contiguous
// runs at exact offsets (cmat + bbase). Zero global atomics.
// Record: x = col(18b) | rowLo(9b)<<18 ; y = fp32 val bits.
// ---------------------------------------------------------------------------
__global__ __launch_bounds__(256) void k_p1c(const int* __restrict__ rows,
                                             const int* __restrict__ cols,
                                             const float* __restrict__ vals,
                                             const int* __restrict__ offs,
                                             const int* __restrict__ bbase,
                                             int2* __restrict__ staged) {
    __shared__ int hist[NBKT];
    __shared__ int lstart[NBKT];
    __shared__ int cursor[NBKT];
    __shared__ int soffs[NBKT];
    __shared__ int sc[512];
    __shared__ int2 st[CHUNK];
    __shared__ unsigned short bkt16[CHUNK];

    int e0 = blockIdx.x * CHUNK;
    int cnt = min(CHUNK, N_EDGES - e0);
    for (int i = threadIdx.x; i < NBKT; i += 256) {
        hist[i] = 0; cursor[i] = 0;
        soffs[i] = offs[i * NBLK + blockIdx.x] + bbase[i];
    }
    sc[threadIdx.x] = 0; sc[threadIdx.x + 256] = 0;
    __syncthreads();
    for (int t = threadIdx.x; t < cnt; t += 256)
        atomicAdd(&hist[rows[e0 + t] >> 9], 1);
    __syncthreads();
    for (int i = threadIdx.x; i < NBKT; i += 256) sc[i] = hist[i];
    __syncthreads();
    // inclusive scan over 512 slots (256 threads x 2, Hillis-Steele)
    for (int off = 1; off < 512; off <<= 1) {
        int a0 = (threadIdx.x >= off)       ? sc[threadIdx.x - off]       : 0;
        int a1 = (threadIdx.x + 256 >= off) ? sc[threadIdx.x + 256 - off] : 0;
        __syncthreads();
        sc[threadIdx.x]       += a0;
        sc[threadIdx.x + 256] += a1;
        __syncthreads();
    }
    for (int i = threadIdx.x; i < NBKT; i += 256) lstart[i] = sc[i] - hist[i];
    __syncthreads();
    // bin into LDS staging
    for (int t = threadIdx.x; t < cnt; t += 256) {
        int r = rows[e0 + t];
        int b = r >> 9;
        int p = lstart[b] + atomicAdd(&cursor[b], 1);
        st[p] = make_int2(cols[e0 + t] | ((r & 511) << 18),
                          __float_as_int(vals[e0 + t]));
        bkt16[p] = (unsigned short)b;
    }
    __syncthreads();
    // flush: consecutive threads in a bucket write consecutive global addrs
    for (int t = threadIdx.x; t < cnt; t += 256) {
        int b = bkt16[t];
        staged[soffs[b] + (t - lstart[b])] = st[t];
    }
}

// ---------------------------------------------------------------------------
// Multisplit p2 (512 threads now — was 1.1 block/CU at 256): row histogram
// from staged records, LDS scan -> local row starts, place records, emit
// counts/startArr.
// ---------------------------------------------------------------------------
__global__ __launch_bounds__(512) void k_p2(const int* __restrict__ bbase,
                                            const int2* __restrict__ staged,
                                            int2* __restrict__ edges,
                                            int* __restrict__ counts,
                                            int* __restrict__ startArr) {
    __shared__ int hist[512];
    __shared__ int lstart[512];
    __shared__ int cur[512];
    __shared__ int sc[512];
    int k = blockIdx.x;
    int rowBase = k << 9;
    int numRows = min(512, N_NODES - rowBase);
    int base = bbase[k];
    int end  = bbase[k + 1];
    int tid = threadIdx.x;
    hist[tid] = 0;
    cur[tid] = 0;
    __syncthreads();
    int cnt = end - base;
    for (int t = tid; t < cnt; t += 512)
        atomicAdd(&hist[((unsigned)staged[base + t].x) >> 18], 1);
    __syncthreads();
    sc[tid] = hist[tid];
    __syncthreads();
    for (int off = 1; off < 512; off <<= 1) {
        int a0 = (tid >= off) ? sc[tid - off] : 0;
        __syncthreads();
        sc[tid] += a0;
        __syncthreads();
    }
    lstart[tid] = sc[tid] - hist[tid];
    __syncthreads();
    for (int t = tid; t < cnt; t += 512) {
        int2 rec = staged[base + t];
        int rl = ((unsigned)rec.x) >> 18;
        int c  = rec.x & 0x3FFFF;
        int off = lstart[rl] + atomicAdd(&cur[rl], 1);
        edges[base + off] = make_int2(c, rec.y);
    }
    for (int i = tid; i < numRows; i += 512) {
        counts[rowBase + i]   = hist[i];
        startArr[rowBase + i] = base + lstart[i];
    }
}

// ---------------------------------------------------------------------------
// Gather SpMM v2 (bf16): TWO rows per wave. Half-wave (32 lanes) = one row;
// lane loads ushort2 (2 dims) -> one gather instruction moves 256B (2 rows).
// Unroll 8 => 2KB of gathers in flight per wave. Branchless half-divergence:
// uniform nmax loop, masked lanes use clamped index + zero weight.
// ---------------------------------------------------------------------------
__global__ __launch_bounds__(256) void k_spmm_csr(const int* __restrict__ startArr,
                                                  const int* __restrict__ counts,
                                                  const int2* __restrict__ edges,
                                                  const unsigned short* __restrict__ cur,
                                                  unsigned short* __restrict__ nxt) {
    int wid  = blockIdx.x * 4 + (threadIdx.x >> 6);   // wave id: rows 2w, 2w+1
    int lane = threadIdx.x & 63;
    int half = lane >> 5;
    int sub  = lane & 31;
    int row  = wid * 2 + half;                        // N_NODES even; grid exact
    int s = startArr[row];
    int n = counts[row];
    int nmax = max(__shfl(n, 0), __shfl(n, 32));
    const ushort2* curp = (const ushort2*)cur;
    float acc0 = 0.f, acc1 = 0.f;
    int j = 0;
    for (; j + 8 <= nmax; j += 8) {
        #pragma unroll
        for (int k = 0; k < 8; k++) {
            int  jj = j + k;
            bool v  = jj < n;
            int2 e  = edges[s + (v ? jj : 0)];
            float w = v ? __int_as_float(e.y) : 0.f;
            ushort2 p = curp[(size_t)e.x * 32 + sub];
            acc0 = fmaf(w, bf2f(p.x), acc0);
            acc1 = fmaf(w, bf2f(p.y), acc1);
        }
    }
    for (; j < nmax; j++) {
        bool v  = j < n;
        int2 e  = edges[s + (v ? j : 0)];
        float w = v ? __int_as_float(e.y) : 0.f;
        ushort2 p = curp[(size_t)e.x * 32 + sub];
        acc0 = fmaf(w, bf2f(p.x), acc0);
        acc1 = fmaf(w, bf2f(p.y), acc1);
    }
    ushort2 o; o.x = f2bf(acc0); o.y = f2bf(acc1);
    *(ushort2*)(nxt + (size_t)row * 64 + 2 * sub) = o;
}

// ---------------------------------------------------------------------------
// Fused layer-3 + layer-2 gather_add, two selected slots per wave.
// ---------------------------------------------------------------------------
__global__ __launch_bounds__(256) void k_spmm_sel(const int* __restrict__ users,
                                                  const int* __restrict__ items,
                                                  const int* __restrict__ startArr,
                                                  const int* __restrict__ counts,
                                                  const int2* __restrict__ edges,
                                                  const unsigned short* __restrict__ cur,
                                                  float* __restrict__ vsel) {
    int wid  = blockIdx.x * 4 + (threadIdx.x >> 6);   // wave: slots 2w, 2w+1
    int lane = threadIdx.x & 63;
    int half = lane >> 5;
    int sub  = lane & 31;
    int slot = wid * 2 + half;                        // < 2*BATCH
    int b, row;
    float* dst;
    if (slot < BATCH) {
        b = slot; row = users[b];
        dst = vsel + (size_t)b * 128 + 2 * sub;
    } else {
        b = slot - BATCH; row = NUM_USERS + items[b];
        dst = vsel + (size_t)b * 128 + 64 + 2 * sub;
    }
    int s = startArr[row];
    int n = counts[row];
    int nmax = max(__shfl(n, 0), __shfl(n, 32));
    const ushort2* curp = (const ushort2*)cur;
    // layer-2 contribution
    ushort2 l2 = curp[(size_t)row * 32 + sub];
    float acc0 = bf2f(l2.x), acc1 = bf2f(l2.y);
    int j = 0;
    for (; j + 8 <= nmax; j += 8) {
        #pragma unroll
        for (int k = 0; k < 8; k++) {
            int  jj = j + k;
            bool v  = jj < n;
            int2 e  = edges[s + (v ? jj : 0)];
            float w = v ? __int_as_float(e.y) : 0.f;
            ushort2 p = curp[(size_t)e.x * 32 + sub];
            acc0 = fmaf(w, bf2f(p.x), acc0);
            acc1 = fmaf(w, bf2f(p.y), acc1);
        }
    }
    for (; j < nmax; j++) {
        bool v  = j < n;
        int2 e  = edges[s + (v ? j : 0)];
        float w = v ? __int_as_float(e.y) : 0.f;
        ushort2 p = curp[(size_t)e.x * 32 + sub];
        acc0 = fmaf(w, bf2f(p.x), acc0);
        acc1 = fmaf(w, bf2f(p.y), acc1);
    }
    float2 d = *(float2*)dst;
    d.x += acc0; d.y += acc1;
    *(float2*)dst = d;
}

// ---------------------------------------------------------------------------
// vsel += bf16 src at selected rows (after layer 1)
// ---------------------------------------------------------------------------
__global__ void k_gather_add(const int* __restrict__ users,
                             const int* __restrict__ items,
                             const unsigned short* __restrict__ src,
                             float* __restrict__ vsel) {
    int t = blockIdx.x * blockDim.x + threadIdx.x;
    int b = t >> 6, d = t & 63;
    vsel[b * 128 + d]      += bf2f(src[(size_t)users[b] * 64 + d]);
    vsel[b * 128 + 64 + d] += bf2f(src[(size_t)(NUM_USERS + items[b]) * 64 + d]);
}

// ---------------------------------------------------------------------------
// MLP head: one THREAD per batch row (register tiling, no cross-lane ops).
// ---------------------------------------------------------------------------
__global__ __launch_bounds__(256) void k_mlp(const float* __restrict__ vsel,
                                             const float* __restrict__ W0,
                                             const float* __restrict__ b0,
                                             const float* __restrict__ W1,
                                             const float* __restrict__ b1,
                                             const float* __restrict__ Wa,
                                             const float* __restrict__ ba,
                                             float* __restrict__ out) {
    __shared__ float sW0[128 * 64];
    __shared__ float sW1[64 * 32];
    __shared__ float sWa[32];
    __shared__ float sb0[64];
    __shared__ float sb1[32];

    for (int i = threadIdx.x; i < 128 * 64; i += 256) sW0[i] = W0[i];
    for (int i = threadIdx.x; i < 64 * 32;  i += 256) sW1[i] = W1[i];
    if (threadIdx.x < 32) sWa[threadIdx.x] = Wa[threadIdx.x];
    if (threadIdx.x < 64) sb0[threadIdx.x] = b0[threadIdx.x];
    if (threadIdx.x >= 64 && threadIdx.x < 96) sb1[threadIdx.x - 64] = b1[threadIdx.x - 64];
    float sba = ba[0];
    __syncthreads();

    int b = blockIdx.x * 256 + threadIdx.x;
    const float4* v4 = (const float4*)(vsel + (size_t)b * 128);

    float h0[64];
    #pragma unroll
    for (int j = 0; j < 64; j++) h0[j] = sb0[j];

    for (int k0 = 0; k0 < 32; k0++) {
        float4 va = v4[k0];
        float a0 = va.x * 0.25f, a1 = va.y * 0.25f;
        float a2 = va.z * 0.25f, a3 = va.w * 0.25f;
        const float* w = &sW0[(k0 * 4) * 64];
        #pragma unroll
        for (int j = 0; j < 64; j++) {
            h0[j] = fmaf(a0, w[j],       h0[j]);
            h0[j] = fmaf(a1, w[64 + j],  h0[j]);
            h0[j] = fmaf(a2, w[128 + j], h0[j]);
            h0[j] = fmaf(a3, w[192 + j], h0[j]);
        }
    }
    #pragma unroll
    for (int j = 0; j < 64; j++) h0[j] = fmaxf(h0[j], 0.f);

    float h1[32];
    #pragma unroll
    for (int j = 0; j < 32; j++) h1[j] = sb1[j];
    for (int k = 0; k < 64; k++) {
        float a = h0[k];
        const float* w = &sW1[k * 32];
        #pragma unroll
        for (int j = 0; j < 32; j++)
            h1[j] = fmaf(a, w[j], h1[j]);
    }

    float logit = sba;
    #pragma unroll
    for (int j = 0; j < 32; j++)
        logit = fmaf(fmaxf(h1[j], 0.f), sWa[j], logit);

    out[b] = 1.0f / (1.0f + expf(-logit));
}

// ---------------------------------------------------------------------------
extern "C" void kernel_launch(void* const* d_in, const int* in_sizes, int n_in,
                              void* d_out, int out_size, void* d_ws, size_t ws_size,
                              hipStream_t stream) {
    const int*   users = (const int*)  d_in[0];
    const int*   items = (const int*)  d_in[1];
    const int*   rows  = (const int*)  d_in[2];
    const int*   cols  = (const int*)  d_in[3];
    const float* vals  = (const float*)d_in[4];
    const float* ue    = (const float*)d_in[5];
    const float* ie    = (const float*)d_in[6];
    const float* W0    = (const float*)d_in[7];
    const float* b0    = (const float*)d_in[8];
    const float* W1    = (const float*)d_in[9];
    const float* b1    = (const float*)d_in[10];
    const float* Wa    = (const float*)d_in[11];
    const float* ba    = (const float*)d_in[12];
    float* out = (float*)d_out;

    const size_t nodeElems = (size_t)N_NODES * LATENT;   // 9.6 M
    char* ws = (char*)d_ws;
    unsigned short* tabA = (unsigned short*)ws;  ws += nodeElems * 2;            // 19.2 MB
    unsigned short* tabB = (unsigned short*)ws;  ws += nodeElems * 2;            // 19.2 MB
    float* vsel = (float*)ws;                    ws += (size_t)BATCH * 128 * 4;  // 8.39 MB
    int2*  edges  = (int2*)ws;                   ws += (size_t)N_EDGES * 8;      // 19.2 MB
    int2*  staged = (int2*)ws;                   ws += (size_t)N_EDGES * 8;      // 19.2 MB
    int* counts   = (int*)ws;                    ws += N_NODES * 4;
    int* startArr = (int*)ws;                    ws += N_NODES * 4;
    int* cmat     = (int*)ws;                    ws += (size_t)NBKT * NBLK * 4;  // 686 KB
    int* btotal   = (int*)ws;                    ws += NBKT * 4;
    int* bbase    = (int*)ws;                    ws += (NBKT + 1) * 4;

    const int gGrid = (BATCH * 64) / 256;

    // bf16 table + fp32 layer-0 selection
    k_concat_bf16<<<(N_NODES * (LATENT / 4) + 255) / 256, 256, 0, stream>>>(
        (const float4*)ue, (const float4*)ie, (ushort4*)tabA);
    k_sel_init<<<gGrid, 256, 0, stream>>>(users, items, ue, ie, vsel);

    // ---- CSR build: zero global atomics ----
    k_p1a<<<NBLK, 256, 0, stream>>>(rows, cmat);
    k_p1b<<<NBKT, 1024, 0, stream>>>(cmat, btotal);
    k_bscan<<<1, 512, 0, stream>>>(btotal, bbase);
    k_p1c<<<NBLK, 256, 0, stream>>>(rows, cols, vals, cmat, bbase, staged);
    k_p2<<<NBKT, 512, 0, stream>>>(bbase, staged, edges, counts, startArr);

    // layer 1: A -> B   (2 rows per wave: N_NODES/2 waves, /4 per block)
    k_spmm_csr<<<N_NODES / 8, 256, 0, stream>>>(startArr, counts, edges, tabA, tabB);
    k_gather_add<<<gGrid, 256, 0, stream>>>(users, items, tabB, vsel);

    // layer 2: B -> A
    k_spmm_csr<<<N_NODES / 8, 256, 0, stream>>>(startArr, counts, edges, tabB, tabA);

    // layer 3 (selected rows) fused with layer-2 gather_add
    k_spmm_sel<<<(2 * BATCH) / 8, 256, 0, stream>>>(users, items, startArr,
                                                    counts, edges, tabA, vsel);

    // MLP head
    k_mlp<<<BATCH / 256, 256, 0, stream>>>(vsel, W0, b0, W1, b1, Wa, ba, out);
}

// Round 11
// 392.314 us; speedup vs baseline: 1.1638x; 1.1638x over previous
//
#include <hip/hip_runtime.h>
#include <math.h>

#define NUM_USERS 100000
#define NUM_ITEMS 50000
#define N_NODES   150000   // NUM_USERS + NUM_ITEMS
#define LATENT    64
#define N_EDGES   2400000
#define BATCH     16384

// Multisplit fill: 4096-edge chunks, 512-row buckets
#define CHUNK 4096
#define NBLK  ((N_EDGES + CHUNK - 1) / CHUNK)   // 586
#define NBKT  ((N_NODES + 511) / 512)           // 293

// bf16 helpers (values small/finite; RNE)
__device__ __forceinline__ unsigned short f2bf(float f) {
    unsigned u = __float_as_uint(f);
    u = (u + 0x7FFF + ((u >> 16) & 1)) >> 16;
    return (unsigned short)u;
}
__device__ __forceinline__ float bf2f(unsigned short h) {
    return __uint_as_float(((unsigned)h) << 16);
}

// ---------------------------------------------------------------------------
// table = bf16(concat(user_emb, item_emb))
// ---------------------------------------------------------------------------
__global__ void k_concat_bf16(const float4* __restrict__ ue,
                              const float4* __restrict__ ie,
                              ushort4* __restrict__ cur) {
    int i = blockIdx.x * blockDim.x + threadIdx.x;
    const int nU4 = NUM_USERS * (LATENT / 4);
    const int nT4 = N_NODES   * (LATENT / 4);
    if (i >= nT4) return;
    float4 v = (i < nU4) ? ue[i] : ie[i - nU4];
    ushort4 o;
    o.x = f2bf(v.x); o.y = f2bf(v.y); o.z = f2bf(v.z); o.w = f2bf(v.w);
    cur[i] = o;
}

// ---------------------------------------------------------------------------
// vsel[b, 0:64] = user_emb[users[b]] ; vsel[b,64:128] = item_emb[items[b]]
// ---------------------------------------------------------------------------
__global__ void k_sel_init(const int* __restrict__ users,
                           const int* __restrict__ items,
                           const float* __restrict__ ue,
                           const float* __restrict__ ie,
                           float* __restrict__ vsel) {
    int t = blockIdx.x * blockDim.x + threadIdx.x;
    int b = t >> 6, d = t & 63;
    vsel[b * 128 + d]      = ue[users[b] * 64 + d];
    vsel[b * 128 + 64 + d] = ie[items[b] * 64 + d];
}

// ---------------------------------------------------------------------------
// Multisplit p1a: per-block bucket histogram -> cmat[bucket][block]
// ---------------------------------------------------------------------------
__global__ __launch_bounds__(256) void k_p1a(const int* __restrict__ rows,
                                             int* __restrict__ cmat) {
    __shared__ int hist[NBKT];
    for (int i = threadIdx.x; i < NBKT; i += 256) hist[i] = 0;
    __syncthreads();
    int e0 = blockIdx.x * CHUNK;
    int cnt = min(CHUNK, N_EDGES - e0);
    for (int t = threadIdx.x; t < cnt; t += 256)
        atomicAdd(&hist[rows[e0 + t] >> 9], 1);
    __syncthreads();
    for (int i = threadIdx.x; i < NBKT; i += 256)
        cmat[i * NBLK + blockIdx.x] = hist[i];
}

// ---------------------------------------------------------------------------
// Multisplit p1b: per-bucket exclusive scan over blocks; emit bucket total.
// ---------------------------------------------------------------------------
__global__ __launch_bounds__(1024) void k_p1b(int* __restrict__ cmat,
                                              int* __restrict__ btotal) {
    __shared__ int sh[1024];
    int k = blockIdx.x;
    int v = (threadIdx.x < NBLK) ? cmat[k * NBLK + threadIdx.x] : 0;
    sh[threadIdx.x] = v;
    __syncthreads();
    for (int off = 1; off < 1024; off <<= 1) {
        int t = (threadIdx.x >= off) ? sh[threadIdx.x - off] : 0;
        __syncthreads();
        sh[threadIdx.x] += t;
        __syncthreads();
    }
    if (threadIdx.x < NBLK)
        cmat[k * NBLK + threadIdx.x] = sh[threadIdx.x] - v;   // exclusive
    if (threadIdx.x == 1023) btotal[k] = sh[1023];
}

// ---------------------------------------------------------------------------
// Bucket-base scan: exclusive scan of 293 bucket totals -> bbase[0..NBKT]
// ---------------------------------------------------------------------------
__global__ __launch_bounds__(512) void k_bscan(const int* __restrict__ btotal,
                                               int* __restrict__ bbase) {
    __shared__ int sh[512];
    int v = (threadIdx.x < NBKT) ? btotal[threadIdx.x] : 0;
    sh[threadIdx.x] = v;
    __syncthreads();
    for (int off = 1; off < 512; off <<= 1) {
        int t = (threadIdx.x >= off) ? sh[threadIdx.x - off] : 0;
        __syncthreads();
        sh[threadIdx.x] += t;
        __syncthreads();
    }
    if (threadIdx.x < NBKT) bbase[threadIdx.x] = sh[threadIdx.x] - v;
    if (threadIdx.x == NBKT) bbase[NBKT] = N_EDGES;
}

// ---------------------------------------------------------------------------
// Multisplit p1c: re-read chunk, bin records in LDS, flush bucket-contiguous
// runs at exact offsets (cmat + bbase). Zero global atomics.
// Record: x = col(18b) | rowLo(9b)<<18 ; y = fp32 val bits.
// ---------------------------------------------------------------------------
__global__ __launch_bounds__(256) void k_p1c(const int* __restrict__ rows,
                                             const int* __restrict__ cols,
                                             const float* __restrict__ vals,
                                             const int* __restrict__ offs,
                                             const int* __restrict__ bbase,
                                             int2* __restrict__ staged) {
    __shared__ int hist[NBKT];
    __shared__ int lstart[NBKT];
    __shared__ int cursor[NBKT];
    __shared__ int soffs[NBKT];
    __shared__ int sc[512];
    __shared__ int2 st[CHUNK];
    __shared__ unsigned short bkt16[CHUNK];

    int e0 = blockIdx.x * CHUNK;
    int cnt = min(CHUNK, N_EDGES - e0);
    for (int i = threadIdx.x; i < NBKT; i += 256) {
        hist[i] = 0; cursor[i] = 0;
        soffs[i] = offs[i * NBLK + blockIdx.x] + bbase[i];
    }
    sc[threadIdx.x] = 0; sc[threadIdx.x + 256] = 0;
    __syncthreads();
    for (int t = threadIdx.x; t < cnt; t += 256)
        atomicAdd(&hist[rows[e0 + t] >> 9], 1);
    __syncthreads();
    for (int i = threadIdx.x; i < NBKT; i += 256) sc[i] = hist[i];
    __syncthreads();
    // inclusive scan over 512 slots (256 threads x 2, Hillis-Steele)
    for (int off = 1; off < 512; off <<= 1) {
        int a0 = (threadIdx.x >= off)       ? sc[threadIdx.x - off]       : 0;
        int a1 = (threadIdx.x + 256 >= off) ? sc[threadIdx.x + 256 - off] : 0;
        __syncthreads();
        sc[threadIdx.x]       += a0;
        sc[threadIdx.x + 256] += a1;
        __syncthreads();
    }
    for (int i = threadIdx.x; i < NBKT; i += 256) lstart[i] = sc[i] - hist[i];
    __syncthreads();
    // bin into LDS staging
    for (int t = threadIdx.x; t < cnt; t += 256) {
        int r = rows[e0 + t];
        int b = r >> 9;
        int p = lstart[b] + atomicAdd(&cursor[b], 1);
        st[p] = make_int2(cols[e0 + t] | ((r & 511) << 18),
                          __float_as_int(vals[e0 + t]));
        bkt16[p] = (unsigned short)b;
    }
    __syncthreads();
    // flush: consecutive threads in a bucket write consecutive global addrs
    for (int t = threadIdx.x; t < cnt; t += 256) {
        int b = bkt16[t];
        staged[soffs[b] + (t - lstart[b])] = st[t];
    }
}

// ---------------------------------------------------------------------------
// Multisplit p2 (512 threads): row histogram from staged records, LDS scan,
// place records row-contiguously, emit counts/startArr.
// ---------------------------------------------------------------------------
__global__ __launch_bounds__(512) void k_p2(const int* __restrict__ bbase,
                                            const int2* __restrict__ staged,
                                            int2* __restrict__ edges,
                                            int* __restrict__ counts,
                                            int* __restrict__ startArr) {
    __shared__ int hist[512];
    __shared__ int lstart[512];
    __shared__ int cur[512];
    __shared__ int sc[512];
    int k = blockIdx.x;
    int rowBase = k << 9;
    int numRows = min(512, N_NODES - rowBase);
    int base = bbase[k];
    int end  = bbase[k + 1];
    int tid = threadIdx.x;
    hist[tid] = 0;
    cur[tid] = 0;
    __syncthreads();
    int cnt = end - base;
    for (int t = tid; t < cnt; t += 512)
        atomicAdd(&hist[((unsigned)staged[base + t].x) >> 18], 1);
    __syncthreads();
    sc[tid] = hist[tid];
    __syncthreads();
    for (int off = 1; off < 512; off <<= 1) {
        int a0 = (tid >= off) ? sc[tid - off] : 0;
        __syncthreads();
        sc[tid] += a0;
        __syncthreads();
    }
    lstart[tid] = sc[tid] - hist[tid];
    __syncthreads();
    for (int t = tid; t < cnt; t += 512) {
        int2 rec = staged[base + t];
        int rl = ((unsigned)rec.x) >> 18;
        int c  = rec.x & 0x3FFFF;
        int off = lstart[rl] + atomicAdd(&cur[rl], 1);
        edges[base + off] = make_int2(c, rec.y);
    }
    for (int i = tid; i < numRows; i += 512) {
        counts[rowBase + i]   = hist[i];
        startArr[rowBase + i] = base + lstart[i];
    }
}

// ---------------------------------------------------------------------------
// Gather SpMM (bf16): one wave per row (wave-uniform edge descriptors),
// unroll 16 => 16 outstanding 128B gathers/wave. Edges via non-temporal
// loads and output via non-temporal store: both are stream-once data —
// keeps L2 free for the random table gathers.
// ---------------------------------------------------------------------------
__global__ __launch_bounds__(256) void k_spmm_csr(const int* __restrict__ startArr,
                                                  const int* __restrict__ counts,
                                                  const int2* __restrict__ edges,
                                                  const unsigned short* __restrict__ cur,
                                                  unsigned short* __restrict__ nxt) {
    int row  = blockIdx.x * 4 + (threadIdx.x >> 6);
    int lane = threadIdx.x & 63;
    if (row >= N_NODES) return;
    row = __builtin_amdgcn_readfirstlane(row);
    int s = __builtin_amdgcn_readfirstlane(startArr[row]);
    int n = __builtin_amdgcn_readfirstlane(counts[row]);
    float acc = 0.f;
    int j = 0;
    for (; j + 16 <= n; j += 16) {
        unsigned long long e[16];
        #pragma unroll
        for (int k = 0; k < 16; k++)
            e[k] = __builtin_nontemporal_load(
                       (const unsigned long long*)&edges[s + j + k]);
        float x[16];
        #pragma unroll
        for (int k = 0; k < 16; k++)
            x[k] = bf2f(cur[(size_t)(unsigned)(e[k] & 0xFFFFFFFFu) * 64 + lane]);
        #pragma unroll
        for (int k = 0; k < 16; k++)
            acc = fmaf(__int_as_float((int)(e[k] >> 32)), x[k], acc);
    }
    for (; j + 4 <= n; j += 4) {
        unsigned long long e[4];
        #pragma unroll
        for (int k = 0; k < 4; k++)
            e[k] = __builtin_nontemporal_load(
                       (const unsigned long long*)&edges[s + j + k]);
        float x[4];
        #pragma unroll
        for (int k = 0; k < 4; k++)
            x[k] = bf2f(cur[(size_t)(unsigned)(e[k] & 0xFFFFFFFFu) * 64 + lane]);
        #pragma unroll
        for (int k = 0; k < 4; k++)
            acc = fmaf(__int_as_float((int)(e[k] >> 32)), x[k], acc);
    }
    for (; j < n; j++) {
        int2 e = edges[s + j];
        acc = fmaf(__int_as_float(e.y), bf2f(cur[(size_t)e.x * 64 + lane]), acc);
    }
    __builtin_nontemporal_store(f2bf(acc), &nxt[(size_t)row * 64 + lane]);
}

// ---------------------------------------------------------------------------
// Fused layer-3 + layer-2 gather_add at selected rows (one slot per wave,
// unroll 16, nt edge loads).
// ---------------------------------------------------------------------------
__global__ __launch_bounds__(256) void k_spmm_sel(const int* __restrict__ users,
                                                  const int* __restrict__ items,
                                                  const int* __restrict__ startArr,
                                                  const int* __restrict__ counts,
                                                  const int2* __restrict__ edges,
                                                  const unsigned short* __restrict__ cur,
                                                  float* __restrict__ vsel) {
    int wave = blockIdx.x * 4 + (threadIdx.x >> 6);
    int lane = threadIdx.x & 63;
    int b, row;
    float* dst;
    if (wave < BATCH) {
        b = wave; row = users[b];
        dst = &vsel[b * 128 + lane];
    } else {
        b = wave - BATCH; row = NUM_USERS + items[b];
        dst = &vsel[b * 128 + 64 + lane];
    }
    int s = startArr[row];
    int n = counts[row];
    float acc = bf2f(cur[(size_t)row * 64 + lane]);   // layer-2 contribution
    int j = 0;
    for (; j + 16 <= n; j += 16) {
        unsigned long long e[16];
        #pragma unroll
        for (int k = 0; k < 16; k++)
            e[k] = __builtin_nontemporal_load(
                       (const unsigned long long*)&edges[s + j + k]);
        float x[16];
        #pragma unroll
        for (int k = 0; k < 16; k++)
            x[k] = bf2f(cur[(size_t)(unsigned)(e[k] & 0xFFFFFFFFu) * 64 + lane]);
        #pragma unroll
        for (int k = 0; k < 16; k++)
            acc = fmaf(__int_as_float((int)(e[k] >> 32)), x[k], acc);
    }
    for (; j + 4 <= n; j += 4) {
        unsigned long long e[4];
        #pragma unroll
        for (int k = 0; k < 4; k++)
            e[k] = __builtin_nontemporal_load(
                       (const unsigned long long*)&edges[s + j + k]);
        float x[4];
        #pragma unroll
        for (int k = 0; k < 4; k++)
            x[k] = bf2f(cur[(size_t)(unsigned)(e[k] & 0xFFFFFFFFu) * 64 + lane]);
        #pragma unroll
        for (int k = 0; k < 4; k++)
            acc = fmaf(__int_as_float((int)(e[k] >> 32)), x[k], acc);
    }
    for (; j < n; j++) {
        int2 e = edges[s + j];
        acc = fmaf(__int_as_float(e.y), bf2f(cur[(size_t)e.x * 64 + lane]), acc);
    }
    *dst += acc;
}

// ---------------------------------------------------------------------------
// vsel += bf16 src at selected rows (after layer 1)
// ---------------------------------------------------------------------------
__global__ void k_gather_add(const int* __restrict__ users,
                             const int* __restrict__ items,
                             const unsigned short* __restrict__ src,
                             float* __restrict__ vsel) {
    int t = blockIdx.x * blockDim.x + threadIdx.x;
    int b = t >> 6, d = t & 63;
    vsel[b * 128 + d]      += bf2f(src[(size_t)users[b] * 64 + d]);
    vsel[b * 128 + 64 + d] += bf2f(src[(size_t)(NUM_USERS + items[b]) * 64 + d]);
}

// ---------------------------------------------------------------------------
// MLP head: one THREAD per batch row (register tiling, no cross-lane ops).
// ---------------------------------------------------------------------------
__global__ __launch_bounds__(256) void k_mlp(const float* __restrict__ vsel,
                                             const float* __restrict__ W0,
                                             const float* __restrict__ b0,
                                             const float* __restrict__ W1,
                                             const float* __restrict__ b1,
                                             const float* __restrict__ Wa,
                                             const float* __restrict__ ba,
                                             float* __restrict__ out) {
    __shared__ float sW0[128 * 64];
    __shared__ float sW1[64 * 32];
    __shared__ float sWa[32];
    __shared__ float sb0[64];
    __shared__ float sb1[32];

    for (int i = threadIdx.x; i < 128 * 64; i += 256) sW0[i] = W0[i];
    for (int i = threadIdx.x; i < 64 * 32;  i += 256) sW1[i] = W1[i];
    if (threadIdx.x < 32) sWa[threadIdx.x] = Wa[threadIdx.x];
    if (threadIdx.x < 64) sb0[threadIdx.x] = b0[threadIdx.x];
    if (threadIdx.x >= 64 && threadIdx.x < 96) sb1[threadIdx.x - 64] = b1[threadIdx.x - 64];
    float sba = ba[0];
    __syncthreads();

    int b = blockIdx.x * 256 + threadIdx.x;
    const float4* v4 = (const float4*)(vsel + (size_t)b * 128);

    float h0[64];
    #pragma unroll
    for (int j = 0; j < 64; j++) h0[j] = sb0[j];

    for (int k0 = 0; k0 < 32; k0++) {
        float4 va = v4[k0];
        float a0 = va.x * 0.25f, a1 = va.y * 0.25f;
        float a2 = va.z * 0.25f, a3 = va.w * 0.25f;
        const float* w = &sW0[(k0 * 4) * 64];
        #pragma unroll
        for (int j = 0; j < 64; j++) {
            h0[j] = fmaf(a0, w[j],       h0[j]);
            h0[j] = fmaf(a1, w[64 + j],  h0[j]);
            h0[j] = fmaf(a2, w[128 + j], h0[j]);
            h0[j] = fmaf(a3, w[192 + j], h0[j]);
        }
    }
    #pragma unroll
    for (int j = 0; j < 64; j++) h0[j] = fmaxf(h0[j], 0.f);

    float h1[32];
    #pragma unroll
    for (int j = 0; j < 32; j++) h1[j] = sb1[j];
    for (int k = 0; k < 64; k++) {
        float a = h0[k];
        const float* w = &sW1[k * 32];
        #pragma unroll
        for (int j = 0; j < 32; j++)
            h1[j] = fmaf(a, w[j], h1[j]);
    }

    float logit = sba;
    #pragma unroll
    for (int j = 0; j < 32; j++)
        logit = fmaf(fmaxf(h1[j], 0.f), sWa[j], logit);

    out[b] = 1.0f / (1.0f + expf(-logit));
}

// ---------------------------------------------------------------------------
extern "C" void kernel_launch(void* const* d_in, const int* in_sizes, int n_in,
                              void* d_out, int out_size, void* d_ws, size_t ws_size,
                              hipStream_t stream) {
    const int*   users = (const int*)  d_in[0];
    const int*   items = (const int*)  d_in[1];
    const int*   rows  = (const int*)  d_in[2];
    const int*   cols  = (const int*)  d_in[3];
    const float* vals  = (const float*)d_in[4];
    const float* ue    = (const float*)d_in[5];
    const float* ie    = (const float*)d_in[6];
    const float* W0    = (const float*)d_in[7];
    const float* b0    = (const float*)d_in[8];
    const float* W1    = (const float*)d_in[9];
    const float* b1    = (const float*)d_in[10];
    const float* Wa    = (const float*)d_in[11];
    const float* ba    = (const float*)d_in[12];
    float* out = (float*)d_out;

    const size_t nodeElems = (size_t)N_NODES * LATENT;   // 9.6 M
    char* ws = (char*)d_ws;
    unsigned short* tabA = (unsigned short*)ws;  ws += nodeElems * 2;            // 19.2 MB
    unsigned short* tabB = (unsigned short*)ws;  ws += nodeElems * 2;            // 19.2 MB
    float* vsel = (float*)ws;                    ws += (size_t)BATCH * 128 * 4;  // 8.39 MB
    int2*  edges  = (int2*)ws;                   ws += (size_t)N_EDGES * 8;      // 19.2 MB
    int2*  staged = (int2*)ws;                   ws += (size_t)N_EDGES * 8;      // 19.2 MB
    int* counts   = (int*)ws;                    ws += N_NODES * 4;
    int* startArr = (int*)ws;                    ws += N_NODES * 4;
    int* cmat     = (int*)ws;                    ws += (size_t)NBKT * NBLK * 4;  // 686 KB
    int* btotal   = (int*)ws;                    ws += NBKT * 4;
    int* bbase    = (int*)ws;                    ws += (NBKT + 1) * 4;

    const int gGrid = (BATCH * 64) / 256;

    // bf16 table + fp32 layer-0 selection
    k_concat_bf16<<<(N_NODES * (LATENT / 4) + 255) / 256, 256, 0, stream>>>(
        (const float4*)ue, (const float4*)ie, (ushort4*)tabA);
    k_sel_init<<<gGrid, 256, 0, stream>>>(users, items, ue, ie, vsel);

    // ---- CSR build: zero global atomics ----
    k_p1a<<<NBLK, 256, 0, stream>>>(rows, cmat);
    k_p1b<<<NBKT, 1024, 0, stream>>>(cmat, btotal);
    k_bscan<<<1, 512, 0, stream>>>(btotal, bbase);
    k_p1c<<<NBLK, 256, 0, stream>>>(rows, cols, vals, cmat, bbase, staged);
    k_p2<<<NBKT, 512, 0, stream>>>(bbase, staged, edges, counts, startArr);

    // layer 1: A -> B (writes every row; no memset needed)
    k_spmm_csr<<<(N_NODES + 3) / 4, 256, 0, stream>>>(startArr, counts, edges, tabA, tabB);
    k_gather_add<<<gGrid, 256, 0, stream>>>(users, items, tabB, vsel);

    // layer 2: B -> A
    k_spmm_csr<<<(N_NODES + 3) / 4, 256, 0, stream>>>(startArr, counts, edges, tabB, tabA);

    // layer 3 (selected rows) fused with layer-2 gather_add
    k_spmm_sel<<<(2 * BATCH) / 4, 256, 0, stream>>>(users, items, startArr,
                                                    counts, edges, tabA, vsel);

    // MLP head
    k_mlp<<<BATCH / 256, 256, 0, stream>>>(vsel, W0, b0, W1, b1, Wa, ba, out);
}

// Round 12
// 389.521 us; speedup vs baseline: 1.1722x; 1.0072x over previous
//
#include <hip/hip_runtime.h>
#include <math.h>

#define NUM_USERS 100000
#define NUM_ITEMS 50000
#define N_NODES   150000   // NUM_USERS + NUM_ITEMS
#define LATENT    64
#define N_EDGES   2400000
#define BATCH     16384

// Multisplit fill: 4096-edge chunks, 512-row buckets
#define CHUNK 4096
#define NBLK  ((N_EDGES + CHUNK - 1) / CHUNK)   // 586
#define NBKT  ((N_NODES + 511) / 512)           // 293

// Per-layer rescale so fp8 SpMM outputs stay in normal range (R5-verified:
// absmax 0.0039 vs threshold 0.0103). layer1 stored x64, layer2 x4096.
#define LAYER_SCALE 64.0f

// ---------------------------------------------------------------------------
// fp8 e4m3fn helpers. Encode: software (runs once per element on store).
// Decode: gfx950 HW cvt op (1 VALU inst), software fallback.
// ---------------------------------------------------------------------------
__device__ __forceinline__ unsigned char f2fp8(float f) {
    float a = fabsf(f);
    unsigned sign = (__float_as_uint(f) >> 24) & 0x80;
    if (a < 0x1p-10f) return (unsigned char)sign;
    if (a > 448.f) a = 448.f;
    int e = (int)((__float_as_uint(a) >> 23) & 0xFF) - 127;
    if (e < -6) e = -6;
    float step = exp2f((float)(e - 3));
    float q = rintf(a / step) * step;
    unsigned qu = __float_as_uint(q);
    int qe = (int)((qu >> 23) & 0xFF) - 127;
    if (qe < -6) return (unsigned char)(sign | (unsigned)(int)rintf(q * 512.0f));
    unsigned qm = (qu >> 20) & 7;
    return (unsigned char)(sign | ((unsigned)(qe + 7) << 3) | qm);
}

__device__ __forceinline__ float fp8d(unsigned int b) {      // low 8 bits
#if __has_builtin(__builtin_amdgcn_cvt_f32_fp8)
    return __builtin_amdgcn_cvt_f32_fp8((int)b, 0);
#else
    unsigned s   = (b & 0x80) << 24;
    unsigned exp = (b >> 3) & 0xF;
    unsigned man = b & 7;
    float normal = __uint_as_float(s | ((exp + 120) << 23) | (man << 20));
    float dn = (float)(int)man * 0x1p-9f;
    dn = (b & 0x80) ? -dn : dn;
    return exp ? normal : dn;
#endif
}

// ---------------------------------------------------------------------------
// table = fp8(concat(user_emb, item_emb)), scale 1
// ---------------------------------------------------------------------------
__global__ void k_concat_fp8(const float4* __restrict__ ue,
                             const float4* __restrict__ ie,
                             uchar4* __restrict__ cur) {
    int i = blockIdx.x * blockDim.x + threadIdx.x;
    const int nU4 = NUM_USERS * (LATENT / 4);
    const int nT4 = N_NODES   * (LATENT / 4);
    if (i >= nT4) return;
    float4 v = (i < nU4) ? ue[i] : ie[i - nU4];
    uchar4 o;
    o.x = f2fp8(v.x); o.y = f2fp8(v.y); o.z = f2fp8(v.z); o.w = f2fp8(v.w);
    cur[i] = o;
}

// ---------------------------------------------------------------------------
// vsel[b, 0:64] = user_emb[users[b]] ; vsel[b,64:128] = item_emb[items[b]]
// (layer-0 kept exact fp32)
// ---------------------------------------------------------------------------
__global__ void k_sel_init(const int* __restrict__ users,
                           const int* __restrict__ items,
                           const float* __restrict__ ue,
                           const float* __restrict__ ie,
                           float* __restrict__ vsel) {
    int t = blockIdx.x * blockDim.x + threadIdx.x;
    int b = t >> 6, d = t & 63;
    vsel[b * 128 + d]      = ue[users[b] * 64 + d];
    vsel[b * 128 + 64 + d] = ie[items[b] * 64 + d];
}

// ---------------------------------------------------------------------------
// Multisplit p1a: per-block bucket histogram -> cmat[bucket][block]
// ---------------------------------------------------------------------------
__global__ __launch_bounds__(256) void k_p1a(const int* __restrict__ rows,
                                             int* __restrict__ cmat) {
    __shared__ int hist[NBKT];
    for (int i = threadIdx.x; i < NBKT; i += 256) hist[i] = 0;
    __syncthreads();
    int e0 = blockIdx.x * CHUNK;
    int cnt = min(CHUNK, N_EDGES - e0);
    for (int t = threadIdx.x; t < cnt; t += 256)
        atomicAdd(&hist[rows[e0 + t] >> 9], 1);
    __syncthreads();
    for (int i = threadIdx.x; i < NBKT; i += 256)
        cmat[i * NBLK + blockIdx.x] = hist[i];
}

// ---------------------------------------------------------------------------
// Multisplit p1b: per-bucket exclusive scan over blocks; emit bucket total.
// ---------------------------------------------------------------------------
__global__ __launch_bounds__(1024) void k_p1b(int* __restrict__ cmat,
                                              int* __restrict__ btotal) {
    __shared__ int sh[1024];
    int k = blockIdx.x;
    int v = (threadIdx.x < NBLK) ? cmat[k * NBLK + threadIdx.x] : 0;
    sh[threadIdx.x] = v;
    __syncthreads();
    for (int off = 1; off < 1024; off <<= 1) {
        int t = (threadIdx.x >= off) ? sh[threadIdx.x - off] : 0;
        __syncthreads();
        sh[threadIdx.x] += t;
        __syncthreads();
    }
    if (threadIdx.x < NBLK)
        cmat[k * NBLK + threadIdx.x] = sh[threadIdx.x] - v;   // exclusive
    if (threadIdx.x == 1023) btotal[k] = sh[1023];
}

// ---------------------------------------------------------------------------
// Bucket-base scan: exclusive scan of 293 bucket totals -> bbase[0..NBKT]
// ---------------------------------------------------------------------------
__global__ __launch_bounds__(512) void k_bscan(const int* __restrict__ btotal,
                                               int* __restrict__ bbase) {
    __shared__ int sh[512];
    int v = (threadIdx.x < NBKT) ? btotal[threadIdx.x] : 0;
    sh[threadIdx.x] = v;
    __syncthreads();
    for (int off = 1; off < 512; off <<= 1) {
        int t = (threadIdx.x >= off) ? sh[threadIdx.x - off] : 0;
        __syncthreads();
        sh[threadIdx.x] += t;
        __syncthreads();
    }
    if (threadIdx.x < NBKT) bbase[threadIdx.x] = sh[threadIdx.x] - v;
    if (threadIdx.x == NBKT) bbase[NBKT] = N_EDGES;
}

// ---------------------------------------------------------------------------
// Multisplit p1c: re-read chunk, bin records in LDS, flush bucket-contiguous
// runs at exact offsets (cmat + bbase). Zero global atomics.
// Record: x = col(18b) | rowLo(9b)<<18 ; y = fp32 val bits.
// ---------------------------------------------------------------------------
__global__ __launch_bounds__(256) void k_p1c(const int* __restrict__ rows,
                                             const int* __restrict__ cols,
                                             const float* __restrict__ vals,
                                             const int* __restrict__ offs,
                                             const int* __restrict__ bbase,
                                             int2* __restrict__ staged) {
    __shared__ int hist[NBKT];
    __shared__ int lstart[NBKT];
    __shared__ int cursor[NBKT];
    __shared__ int soffs[NBKT];
    __shared__ int sc[512];
    __shared__ int2 st[CHUNK];
    __shared__ unsigned short bkt16[CHUNK];

    int e0 = blockIdx.x * CHUNK;
    int cnt = min(CHUNK, N_EDGES - e0);
    for (int i = threadIdx.x; i < NBKT; i += 256) {
        hist[i] = 0; cursor[i] = 0;
        soffs[i] = offs[i * NBLK + blockIdx.x] + bbase[i];
    }
    sc[threadIdx.x] = 0; sc[threadIdx.x + 256] = 0;
    __syncthreads();
    for (int t = threadIdx.x; t < cnt; t += 256)
        atomicAdd(&hist[rows[e0 + t] >> 9], 1);
    __syncthreads();
    for (int i = threadIdx.x; i < NBKT; i += 256) sc[i] = hist[i];
    __syncthreads();
    // inclusive scan over 512 slots (256 threads x 2, Hillis-Steele)
    for (int off = 1; off < 512; off <<= 1) {
        int a0 = (threadIdx.x >= off)       ? sc[threadIdx.x - off]       : 0;
        int a1 = (threadIdx.x + 256 >= off) ? sc[threadIdx.x + 256 - off] : 0;
        __syncthreads();
        sc[threadIdx.x]       += a0;
        sc[threadIdx.x + 256] += a1;
        __syncthreads();
    }
    for (int i = threadIdx.x; i < NBKT; i += 256) lstart[i] = sc[i] - hist[i];
    __syncthreads();
    // bin into LDS staging
    for (int t = threadIdx.x; t < cnt; t += 256) {
        int r = rows[e0 + t];
        int b = r >> 9;
        int p = lstart[b] + atomicAdd(&cursor[b], 1);
        st[p] = make_int2(cols[e0 + t] | ((r & 511) << 18),
                          __float_as_int(vals[e0 + t]));
        bkt16[p] = (unsigned short)b;
    }
    __syncthreads();
    // flush: consecutive threads in a bucket write consecutive global addrs
    for (int t = threadIdx.x; t < cnt; t += 256) {
        int b = bkt16[t];
        staged[soffs[b] + (t - lstart[b])] = st[t];
    }
}

// ---------------------------------------------------------------------------
// Multisplit p2 (512 threads): row histogram from staged records, LDS scan,
// place records row-contiguously, emit counts/startArr.
// ---------------------------------------------------------------------------
__global__ __launch_bounds__(512) void k_p2(const int* __restrict__ bbase,
                                            const int2* __restrict__ staged,
                                            int2* __restrict__ edges,
                                            int* __restrict__ counts,
                                            int* __restrict__ startArr) {
    __shared__ int hist[512];
    __shared__ int lstart[512];
    __shared__ int cur[512];
    __shared__ int sc[512];
    int k = blockIdx.x;
    int rowBase = k << 9;
    int numRows = min(512, N_NODES - rowBase);
    int base = bbase[k];
    int end  = bbase[k + 1];
    int tid = threadIdx.x;
    hist[tid] = 0;
    cur[tid] = 0;
    __syncthreads();
    int cnt = end - base;
    for (int t = tid; t < cnt; t += 512)
        atomicAdd(&hist[((unsigned)staged[base + t].x) >> 18], 1);
    __syncthreads();
    sc[tid] = hist[tid];
    __syncthreads();
    for (int off = 1; off < 512; off <<= 1) {
        int a0 = (tid >= off) ? sc[tid - off] : 0;
        __syncthreads();
        sc[tid] += a0;
        __syncthreads();
    }
    lstart[tid] = sc[tid] - hist[tid];
    __syncthreads();
    for (int t = tid; t < cnt; t += 512) {
        int2 rec = staged[base + t];
        int rl = ((unsigned)rec.x) >> 18;
        int c  = rec.x & 0x3FFFF;
        int off = lstart[rl] + atomicAdd(&cur[rl], 1);
        edges[base + off] = make_int2(c, rec.y);
    }
    for (int i = tid; i < numRows; i += 512) {
        counts[rowBase + i]   = hist[i];
        startArr[rowBase + i] = base + lstart[i];
    }
}

// ---------------------------------------------------------------------------
// Gather SpMM (fp8 table): one wave per row (wave-uniform edge descriptors,
// R9 structure), unroll 8. Wave gather = 64B = ONE cacheline per edge.
// Output stored at (input scale * LAYER_SCALE).
// ---------------------------------------------------------------------------
__global__ __launch_bounds__(256) void k_spmm_csr(const int* __restrict__ startArr,
                                                  const int* __restrict__ counts,
                                                  const int2* __restrict__ edges,
                                                  const unsigned char* __restrict__ cur,
                                                  unsigned char* __restrict__ nxt) {
    int row  = blockIdx.x * 4 + (threadIdx.x >> 6);
    int lane = threadIdx.x & 63;
    if (row >= N_NODES) return;
    row = __builtin_amdgcn_readfirstlane(row);
    int s = __builtin_amdgcn_readfirstlane(startArr[row]);
    int n = __builtin_amdgcn_readfirstlane(counts[row]);
    float acc = 0.f;
    int j = 0;
    for (; j + 8 <= n; j += 8) {
        int2 e0 = edges[s + j + 0];
        int2 e1 = edges[s + j + 1];
        int2 e2 = edges[s + j + 2];
        int2 e3 = edges[s + j + 3];
        int2 e4 = edges[s + j + 4];
        int2 e5 = edges[s + j + 5];
        int2 e6 = edges[s + j + 6];
        int2 e7 = edges[s + j + 7];
        unsigned x0 = cur[(size_t)e0.x * 64 + lane];
        unsigned x1 = cur[(size_t)e1.x * 64 + lane];
        unsigned x2 = cur[(size_t)e2.x * 64 + lane];
        unsigned x3 = cur[(size_t)e3.x * 64 + lane];
        unsigned x4 = cur[(size_t)e4.x * 64 + lane];
        unsigned x5 = cur[(size_t)e5.x * 64 + lane];
        unsigned x6 = cur[(size_t)e6.x * 64 + lane];
        unsigned x7 = cur[(size_t)e7.x * 64 + lane];
        acc = fmaf(__int_as_float(e0.y), fp8d(x0), acc);
        acc = fmaf(__int_as_float(e1.y), fp8d(x1), acc);
        acc = fmaf(__int_as_float(e2.y), fp8d(x2), acc);
        acc = fmaf(__int_as_float(e3.y), fp8d(x3), acc);
        acc = fmaf(__int_as_float(e4.y), fp8d(x4), acc);
        acc = fmaf(__int_as_float(e5.y), fp8d(x5), acc);
        acc = fmaf(__int_as_float(e6.y), fp8d(x6), acc);
        acc = fmaf(__int_as_float(e7.y), fp8d(x7), acc);
    }
    for (; j + 4 <= n; j += 4) {
        int2 e0 = edges[s + j + 0];
        int2 e1 = edges[s + j + 1];
        int2 e2 = edges[s + j + 2];
        int2 e3 = edges[s + j + 3];
        unsigned x0 = cur[(size_t)e0.x * 64 + lane];
        unsigned x1 = cur[(size_t)e1.x * 64 + lane];
        unsigned x2 = cur[(size_t)e2.x * 64 + lane];
        unsigned x3 = cur[(size_t)e3.x * 64 + lane];
        acc = fmaf(__int_as_float(e0.y), fp8d(x0), acc);
        acc = fmaf(__int_as_float(e1.y), fp8d(x1), acc);
        acc = fmaf(__int_as_float(e2.y), fp8d(x2), acc);
        acc = fmaf(__int_as_float(e3.y), fp8d(x3), acc);
    }
    for (; j < n; j++) {
        int2 e = edges[s + j];
        acc = fmaf(__int_as_float(e.y), fp8d(cur[(size_t)e.x * 64 + lane]), acc);
    }
    nxt[(size_t)row * 64 + lane] = f2fp8(acc * LAYER_SCALE);
}

// ---------------------------------------------------------------------------
// Fused layer-3 + layer-2 gather_add at selected rows.
// cur = layer-2 output at scale 4096; both terms descaled by 1/4096.
// ---------------------------------------------------------------------------
__global__ __launch_bounds__(256) void k_spmm_sel(const int* __restrict__ users,
                                                  const int* __restrict__ items,
                                                  const int* __restrict__ startArr,
                                                  const int* __restrict__ counts,
                                                  const int2* __restrict__ edges,
                                                  const unsigned char* __restrict__ cur,
                                                  float* __restrict__ vsel) {
    int wave = blockIdx.x * 4 + (threadIdx.x >> 6);
    int lane = threadIdx.x & 63;
    int b, row;
    float* dst;
    if (wave < BATCH) {
        b = wave; row = users[b];
        dst = &vsel[b * 128 + lane];
    } else {
        b = wave - BATCH; row = NUM_USERS + items[b];
        dst = &vsel[b * 128 + 64 + lane];
    }
    int s = startArr[row];
    int n = counts[row];
    float acc = fp8d(cur[(size_t)row * 64 + lane]);   // layer-2 contribution
    int j = 0;
    for (; j + 8 <= n; j += 8) {
        int2 e0 = edges[s + j + 0];
        int2 e1 = edges[s + j + 1];
        int2 e2 = edges[s + j + 2];
        int2 e3 = edges[s + j + 3];
        int2 e4 = edges[s + j + 4];
        int2 e5 = edges[s + j + 5];
        int2 e6 = edges[s + j + 6];
        int2 e7 = edges[s + j + 7];
        unsigned x0 = cur[(size_t)e0.x * 64 + lane];
        unsigned x1 = cur[(size_t)e1.x * 64 + lane];
        unsigned x2 = cur[(size_t)e2.x * 64 + lane];
        unsigned x3 = cur[(size_t)e3.x * 64 + lane];
        unsigned x4 = cur[(size_t)e4.x * 64 + lane];
        unsigned x5 = cur[(size_t)e5.x * 64 + lane];
        unsigned x6 = cur[(size_t)e6.x * 64 + lane];
        unsigned x7 = cur[(size_t)e7.x * 64 + lane];
        acc = fmaf(__int_as_float(e0.y), fp8d(x0), acc);
        acc = fmaf(__int_as_float(e1.y), fp8d(x1), acc);
        acc = fmaf(__int_as_float(e2.y), fp8d(x2), acc);
        acc = fmaf(__int_as_float(e3.y), fp8d(x3), acc);
        acc = fmaf(__int_as_float(e4.y), fp8d(x4), acc);
        acc = fmaf(__int_as_float(e5.y), fp8d(x5), acc);
        acc = fmaf(__int_as_float(e6.y), fp8d(x6), acc);
        acc = fmaf(__int_as_float(e7.y), fp8d(x7), acc);
    }
    for (; j < n; j++) {
        int2 e = edges[s + j];
        acc = fmaf(__int_as_float(e.y), fp8d(cur[(size_t)e.x * 64 + lane]), acc);
    }
    *dst += acc * (1.0f / (LAYER_SCALE * LAYER_SCALE));
}

// ---------------------------------------------------------------------------
// vsel += src (fp8, scale 64) at selected rows — after layer 1
// ---------------------------------------------------------------------------
__global__ void k_gather_add(const int* __restrict__ users,
                             const int* __restrict__ items,
                             const unsigned char* __restrict__ src,
                             float* __restrict__ vsel) {
    int t = blockIdx.x * blockDim.x + threadIdx.x;
    int b = t >> 6, d = t & 63;
    vsel[b * 128 + d]      += fp8d(src[(size_t)users[b] * 64 + d]) * (1.0f / LAYER_SCALE);
    vsel[b * 128 + 64 + d] += fp8d(src[(size_t)(NUM_USERS + items[b]) * 64 + d]) * (1.0f / LAYER_SCALE);
}

// ---------------------------------------------------------------------------
// MLP head: one THREAD per batch row (register tiling, no cross-lane ops).
// ---------------------------------------------------------------------------
__global__ __launch_bounds__(256) void k_mlp(const float* __restrict__ vsel,
                                             const float* __restrict__ W0,
                                             const float* __restrict__ b0,
                                             const float* __restrict__ W1,
                                             const float* __restrict__ b1,
                                             const float* __restrict__ Wa,
                                             const float* __restrict__ ba,
                                             float* __restrict__ out) {
    __shared__ float sW0[128 * 64];
    __shared__ float sW1[64 * 32];
    __shared__ float sWa[32];
    __shared__ float sb0[64];
    __shared__ float sb1[32];

    for (int i = threadIdx.x; i < 128 * 64; i += 256) sW0[i] = W0[i];
    for (int i = threadIdx.x; i < 64 * 32;  i += 256) sW1[i] = W1[i];
    if (threadIdx.x < 32) sWa[threadIdx.x] = Wa[threadIdx.x];
    if (threadIdx.x < 64) sb0[threadIdx.x] = b0[threadIdx.x];
    if (threadIdx.x >= 64 && threadIdx.x < 96) sb1[threadIdx.x - 64] = b1[threadIdx.x - 64];
    float sba = ba[0];
    __syncthreads();

    int b = blockIdx.x * 256 + threadIdx.x;
    const float4* v4 = (const float4*)(vsel + (size_t)b * 128);

    float h0[64];
    #pragma unroll
    for (int j = 0; j < 64; j++) h0[j] = sb0[j];

    for (int k0 = 0; k0 < 32; k0++) {
        float4 va = v4[k0];
        float a0 = va.x * 0.25f, a1 = va.y * 0.25f;
        float a2 = va.z * 0.25f, a3 = va.w * 0.25f;
        const float* w = &sW0[(k0 * 4) * 64];
        #pragma unroll
        for (int j = 0; j < 64; j++) {
            h0[j] = fmaf(a0, w[j],       h0[j]);
            h0[j] = fmaf(a1, w[64 + j],  h0[j]);
            h0[j] = fmaf(a2, w[128 + j], h0[j]);
            h0[j] = fmaf(a3, w[192 + j], h0[j]);
        }
    }
    #pragma unroll
    for (int j = 0; j < 64; j++) h0[j] = fmaxf(h0[j], 0.f);

    float h1[32];
    #pragma unroll
    for (int j = 0; j < 32; j++) h1[j] = sb1[j];
    for (int k = 0; k < 64; k++) {
        float a = h0[k];
        const float* w = &sW1[k * 32];
        #pragma unroll
        for (int j = 0; j < 32; j++)
            h1[j] = fmaf(a, w[j], h1[j]);
    }

    float logit = sba;
    #pragma unroll
    for (int j = 0; j < 32; j++)
        logit = fmaf(fmaxf(h1[j], 0.f), sWa[j], logit);

    out[b] = 1.0f / (1.0f + expf(-logit));
}

// ---------------------------------------------------------------------------
extern "C" void kernel_launch(void* const* d_in, const int* in_sizes, int n_in,
                              void* d_out, int out_size, void* d_ws, size_t ws_size,
                              hipStream_t stream) {
    const int*   users = (const int*)  d_in[0];
    const int*   items = (const int*)  d_in[1];
    const int*   rows  = (const int*)  d_in[2];
    const int*   cols  = (const int*)  d_in[3];
    const float* vals  = (const float*)d_in[4];
    const float* ue    = (const float*)d_in[5];
    const float* ie    = (const float*)d_in[6];
    const float* W0    = (const float*)d_in[7];
    const float* b0    = (const float*)d_in[8];
    const float* W1    = (const float*)d_in[9];
    const float* b1    = (const float*)d_in[10];
    const float* Wa    = (const float*)d_in[11];
    const float* ba    = (const float*)d_in[12];
    float* out = (float*)d_out;

    const size_t nodeElems = (size_t)N_NODES * LATENT;   // 9.6 M
    char* ws = (char*)d_ws;
    unsigned char* tabA = (unsigned char*)ws;    ws += nodeElems;                // 9.6 MB
    unsigned char* tabB = (unsigned char*)ws;    ws += nodeElems;                // 9.6 MB
    float* vsel = (float*)ws;                    ws += (size_t)BATCH * 128 * 4;  // 8.39 MB
    int2*  edges  = (int2*)ws;                   ws += (size_t)N_EDGES * 8;      // 19.2 MB
    int2*  staged = (int2*)ws;                   ws += (size_t)N_EDGES * 8;      // 19.2 MB
    int* counts   = (int*)ws;                    ws += N_NODES * 4;
    int* startArr = (int*)ws;                    ws += N_NODES * 4;
    int* cmat     = (int*)ws;                    ws += (size_t)NBKT * NBLK * 4;  // 686 KB
    int* btotal   = (int*)ws;                    ws += NBKT * 4;
    int* bbase    = (int*)ws;                    ws += (NBKT + 1) * 4;

    const int gGrid = (BATCH * 64) / 256;

    // fp8 table + fp32 layer-0 selection
    k_concat_fp8<<<(N_NODES * (LATENT / 4) + 255) / 256, 256, 0, stream>>>(
        (const float4*)ue, (const float4*)ie, (uchar4*)tabA);
    k_sel_init<<<gGrid, 256, 0, stream>>>(users, items, ue, ie, vsel);

    // ---- CSR build: zero global atomics ----
    k_p1a<<<NBLK, 256, 0, stream>>>(rows, cmat);
    k_p1b<<<NBKT, 1024, 0, stream>>>(cmat, btotal);
    k_bscan<<<1, 512, 0, stream>>>(btotal, bbase);
    k_p1c<<<NBLK, 256, 0, stream>>>(rows, cols, vals, cmat, bbase, staged);
    k_p2<<<NBKT, 512, 0, stream>>>(bbase, staged, edges, counts, startArr);

    // layer 1: A -> B (writes every row; no memset needed)
    k_spmm_csr<<<(N_NODES + 3) / 4, 256, 0, stream>>>(startArr, counts, edges, tabA, tabB);
    k_gather_add<<<gGrid, 256, 0, stream>>>(users, items, tabB, vsel);

    // layer 2: B -> A
    k_spmm_csr<<<(N_NODES + 3) / 4, 256, 0, stream>>>(startArr, counts, edges, tabB, tabA);

    // layer 3 (selected rows) fused with layer-2 gather_add
    k_spmm_sel<<<(2 * BATCH) / 4, 256, 0, stream>>>(users, items, startArr,
                                                    counts, edges, tabA, vsel);

    // MLP head
    k_mlp<<<BATCH / 256, 256, 0, stream>>>(vsel, W0, b0, W1, b1, Wa, ba, out);
}